// Round 7
// baseline (248.524 us; speedup 1.0000x reference)
//
#include <hip/hip_runtime.h>

#define B_ 8
#define C_ 512
#define N_ 2304
#define CQ 64

typedef float f32x4 __attribute__((ext_vector_type(4)));
typedef float f32x16 __attribute__((ext_vector_type(16)));
typedef short bf16x8 __attribute__((ext_vector_type(8)));
typedef unsigned short u16x8 __attribute__((ext_vector_type(8)));
typedef int i32x4 __attribute__((ext_vector_type(4)));

__device__ __forceinline__ unsigned short f2bf(float f){
  union { float f; unsigned int u; } v; v.f = f;
  unsigned int r = (v.u + 0x7fffu + ((v.u >> 16) & 1u)) >> 16;
  return (unsigned short)r;
}

// ---------------- transpose: x [B][C][N] f32 -> xt [B][N][C] bf16 ----------------
__global__ __launch_bounds__(256) void k_transpose(const float* __restrict__ x,
                                                   unsigned short* __restrict__ xt){
  __shared__ float T[64*68];
  int i = blockIdx.x;
  int b = i & 7; int r = i >> 3;
  int ct = r & 7, nt = r >> 3;
  int c0 = ct << 6, n0 = nt << 6;
  int t = threadIdx.x;
  {
    int c = t >> 2, nn = (t & 3) << 4;
    const float* src = x + ((size_t)b*C_ + c0 + c)*N_ + n0 + nn;
    #pragma unroll
    for (int q = 0; q < 4; q++){
      f32x4 v = *(const f32x4*)(src + q*4);
      *(f32x4*)&T[c*68 + nn + q*4] = v;
    }
  }
  __syncthreads();
  {
    int n = t >> 2, cs = (t & 3) << 4;
    u16x8 h0, h1;
    #pragma unroll
    for (int ii = 0; ii < 8; ii++) h0[ii] = f2bf(T[(cs+ii)*68 + n]);
    #pragma unroll
    for (int ii = 0; ii < 8; ii++) h1[ii] = f2bf(T[(cs+8+ii)*68 + n]);
    unsigned short* d = xt + ((size_t)b*N_ + n0 + n)*C_ + c0 + cs;
    *(u16x8*)d = h0;
    *(u16x8*)(d + 8) = h1;
  }
}

// ---------------- projection GEMM ----------------
// MODE 0: Q -> center over o, scale log2e/512, store [B][N][64] bf16
// MODE 1: K -> store [B][N][64] bf16
// MODE 2: V -> store [B][C][N] bf16 with m-perm (bit2<->bit3 pairing)
template<int MODE>
__global__ __launch_bounds__(256) void k_proj(const unsigned short* __restrict__ xt,
                                              const float* __restrict__ Wm,
                                              const float* __restrict__ bias,
                                              unsigned short* __restrict__ outw){
  __shared__ short Al[64*40];
  __shared__ short Bl[64*40];
  __shared__ float T[64*68];
  int i = blockIdx.x;
  int b = i & 7; int r = i >> 3;
  int nt, o0;
  if (MODE == 2){ nt = r >> 3; o0 = (r & 7) << 6; } else { nt = r; o0 = 0; }
  int n0 = nt << 6;
  int t = threadIdx.x; int w = t >> 6; int l = t & 63;
  int cl = l & 15, g = l >> 4;
  int col = (w << 4) + cl;

  f32x4 acc[4];
  #pragma unroll
  for (int nf = 0; nf < 4; nf++) acc[nf] = (f32x4){0.f,0.f,0.f,0.f};

  for (int kk = 0; kk < 16; kk++){
    int c0k = kk << 5;
    {
      int n = t >> 2, cs8 = (t & 3) << 3;
      u16x8 v = *(const u16x8*)(xt + ((size_t)b*N_ + n0 + n)*C_ + c0k + cs8);
      *(u16x8*)&Al[n*40 + cs8] = v;
    }
    {
      int o = t >> 2, cs8 = (t & 3) << 3;
      const float* s = Wm + (size_t)(o0 + o)*C_ + c0k + cs8;
      f32x4 v0 = *(const f32x4*)s;
      f32x4 v1 = *(const f32x4*)(s + 4);
      u16x8 h;
      #pragma unroll
      for (int j = 0; j < 4; j++) h[j] = f2bf(v0[j]);
      #pragma unroll
      for (int j = 0; j < 4; j++) h[4+j] = f2bf(v1[j]);
      *(u16x8*)&Bl[o*40 + cs8] = h;
    }
    __syncthreads();
    bf16x8 bfr = *(const bf16x8*)&Bl[col*40 + (g << 3)];
    #pragma unroll
    for (int nf = 0; nf < 4; nf++){
      bf16x8 afr = *(const bf16x8*)&Al[((nf << 4) + cl)*40 + (g << 3)];
      acc[nf] = __builtin_amdgcn_mfma_f32_16x16x32_bf16(afr, bfr, acc[nf], 0, 0, 0);
    }
    __syncthreads();
  }

  float bvv = bias[o0 + col];
  #pragma unroll
  for (int nf = 0; nf < 4; nf++)
    #pragma unroll
    for (int rr = 0; rr < 4; rr++)
      T[((nf << 4) + (g << 2) + rr)*68 + col] = acc[nf][rr] + bvv;
  __syncthreads();

  if (MODE == 2){
    int o = t >> 2, j = t & 3;
    u16x8 h0, h1;
    #pragma unroll
    for (int ii = 0; ii < 8; ii++){
      int q2 = (ii & 3) | ((ii & 4) << 1);
      h0[ii] = f2bf(T[(j*16 + q2)*68 + o]);
    }
    #pragma unroll
    for (int ii = 0; ii < 8; ii++){
      int q2 = ((ii & 3) | ((ii & 4) << 1)) + 4;
      h1[ii] = f2bf(T[(j*16 + q2)*68 + o]);
    }
    unsigned short* d = outw + ((size_t)b*C_ + o0 + o)*N_ + n0 + (j << 4);
    *(u16x8*)d = h0;
    *(u16x8*)(d + 8) = h1;
  } else {
    int n = t >> 2, j = t & 3;
    float vals[16]; float s = 0.f;
    #pragma unroll
    for (int ii = 0; ii < 16; ii++){ vals[ii] = T[n*68 + (j << 4) + ii]; s += vals[ii]; }
    s += __shfl_xor(s, 1); s += __shfl_xor(s, 2);
    float mean = (MODE == 0) ? s * (1.f/64.f) : 0.f;
    float scl  = (MODE == 0) ? (1.44269504089f/512.f) : 1.f;
    u16x8 h0, h1;
    #pragma unroll
    for (int ii = 0; ii < 8; ii++) h0[ii] = f2bf((vals[ii]   - mean) * scl);
    #pragma unroll
    for (int ii = 0; ii < 8; ii++) h1[ii] = f2bf((vals[8+ii] - mean) * scl);
    unsigned short* d = outw + ((size_t)b*N_ + n0 + n)*CQ + (j << 4);
    *(u16x8*)d = h0;
    *(u16x8*)(d + 8) = h1;
  }
}

// ---------------- fused attention: S + exp + PV + normalize + residual ----------------
// grid: (qt*2 + ch)*8 + b  -> 36*2*8 = 576 blocks, 256 thr (4 waves).
// Block: 64 q-rows, 256-channel half. Step = 128 m-values, 18 steps, 1 barrier/step.
// Wave w: produces S/P for step-local m-chunk [32w, 32w+32) (both 32-row n-cols),
// consumes P (all chunks, via dbuf LDS) for its own c-slice ch*256+w*64.
// K, V read directly global->reg (per-batch slabs are XCD-L2-resident).
__global__ __launch_bounds__(256, 2) void k_attn(const unsigned short* __restrict__ qw,
                                                 const unsigned short* __restrict__ kw,
                                                 const unsigned short* __restrict__ vw,
                                                 const float* __restrict__ x,
                                                 const float* __restrict__ gamma_p,
                                                 float* __restrict__ out){
  __shared__ __attribute__((aligned(16))) short Pl2[2][8*64*16];   // 2 x 16 KB
  __shared__ float lred[4][64];

  int i = blockIdx.x;
  int b = i & 7; int ch = (i >> 3) & 1; int qt = i >> 4;
  int n0 = qt << 6;
  int t = threadIdx.x; int w = t >> 6; int l = t & 63;
  int h = l >> 5, ln = l & 31;

  const size_t bN = (size_t)b*N_;
  // Q fragments (persistent): qf[nn][kq] = Q[n0+nn*32+ln][kq*16 + h*8 ..]
  bf16x8 qf[2][4];
  #pragma unroll
  for (int nn = 0; nn < 2; nn++)
    #pragma unroll
    for (int kq = 0; kq < 4; kq++)
      qf[nn][kq] = *(const bf16x8*)(qw + (bN + n0 + nn*32 + ln)*CQ + kq*16 + h*8);

  const unsigned short* kbase = kw + (bN + w*32 + ln)*CQ + h*8;                    // + m*CQ + kq*16
  const unsigned short* vbase = vw + ((size_t)b*C_ + ch*256 + w*64 + ln)*N_ + h*8; // + cf*32*N + m0 + kf*16

  f32x16 acc[2][2];
  #pragma unroll
  for (int cf = 0; cf < 2; cf++)
    #pragma unroll
    for (int nn = 0; nn < 2; nn++)
      #pragma unroll
      for (int rr = 0; rr < 16; rr++) acc[cf][nn][rr] = 0.f;
  float lsum0 = 0.f, lsum1 = 0.f;

  bf16x8 kfA[4], kfB[4];
  #pragma unroll
  for (int kq = 0; kq < 4; kq++) kfA[kq] = *(const bf16x8*)(kbase + kq*16);

  #define FSTEP(KFC, KFN, MT, PB)                                                \
  {                                                                              \
    const int m0 = (MT)*128;                                                     \
    const int m1n = ((MT) + 1 < 18) ? ((MT) + 1)*128 : 0;                        \
    char* Pb = (char*)Pl2[PB];                                                   \
    /* V(t) loads (consumed after barrier) */                                    \
    bf16x8 vf[2][8];                                                             \
    _Pragma("unroll")                                                            \
    for (int cf = 0; cf < 2; cf++)                                               \
      _Pragma("unroll")                                                          \
      for (int kfi = 0; kfi < 8; kfi++)                                          \
        vf[cf][kfi] = *(const bf16x8*)(vbase + (size_t)cf*32*N_ + m0 + kfi*16);  \
    /* K(t+1) prefetch */                                                        \
    _Pragma("unroll")                                                            \
    for (int kq = 0; kq < 4; kq++)                                               \
      KFN[kq] = *(const bf16x8*)(kbase + (size_t)m1n*CQ + kq*16);                \
    /* S + exp + pack + P-store, nn = 0,1 */                                     \
    _Pragma("unroll")                                                            \
    for (int nn = 0; nn < 2; nn++){                                              \
      f32x16 sv;                                                                 \
      _Pragma("unroll")                                                          \
      for (int rr = 0; rr < 16; rr++) sv[rr] = 0.f;                              \
      _Pragma("unroll")                                                          \
      for (int kq = 0; kq < 4; kq++)                                             \
        sv = __builtin_amdgcn_mfma_f32_32x32x16_bf16(KFC[kq], qf[nn][kq], sv, 0, 0, 0); \
      float e[16];                                                               \
      _Pragma("unroll")                                                          \
      for (int rr = 0; rr < 16; rr++) e[rr] = exp2f(sv[rr]);                     \
      float s0=e[0]+e[1], s1=e[2]+e[3], s2=e[4]+e[5], s3=e[6]+e[7];              \
      float s4=e[8]+e[9], s5=e[10]+e[11], s6=e[12]+e[13], s7=e[14]+e[15];        \
      float q0=s0+s1, q1=s2+s3, q2=s4+s5, q3=s6+s7;                              \
      if (nn == 0) lsum0 += (q0+q1)+(q2+q3); else lsum1 += (q0+q1)+(q2+q3);      \
      unsigned int pd[8];                                                        \
      _Pragma("unroll")                                                          \
      for (int j = 0; j < 8; j++)                                                \
        asm("v_cvt_pk_bf16_f32 %0, %1, %2" : "=v"(pd[j]) : "v"(e[2*j]), "v"(e[2*j+1])); \
      i32x4 lo = (i32x4){(int)pd[0],(int)pd[1],(int)pd[2],(int)pd[3]};           \
      i32x4 hi = (i32x4){(int)pd[4],(int)pd[5],(int)pd[6],(int)pd[7]};           \
      *(i32x4*)(Pb + (((2*w  )*64 + nn*32 + ln)*32 + h*16)) = lo;                \
      *(i32x4*)(Pb + (((2*w+1)*64 + nn*32 + ln)*32 + h*16)) = hi;                \
    }                                                                            \
    asm volatile("s_waitcnt lgkmcnt(0)" ::: "memory");                           \
    __builtin_amdgcn_s_barrier();                                                \
    __builtin_amdgcn_sched_barrier(0);                                           \
    /* PV: 32 MFMA on own c-slice */                                             \
    _Pragma("unroll")                                                            \
    for (int kfi = 0; kfi < 8; kfi++){                                           \
      bf16x8 bf0 = *(const bf16x8*)(Pb + ((kfi*64 + ln)*32 + h*16));             \
      bf16x8 bf1 = *(const bf16x8*)(Pb + ((kfi*64 + 32 + ln)*32 + h*16));        \
      acc[0][0] = __builtin_amdgcn_mfma_f32_32x32x16_bf16(vf[0][kfi], bf0, acc[0][0], 0, 0, 0); \
      acc[1][0] = __builtin_amdgcn_mfma_f32_32x32x16_bf16(vf[1][kfi], bf0, acc[1][0], 0, 0, 0); \
      acc[0][1] = __builtin_amdgcn_mfma_f32_32x32x16_bf16(vf[0][kfi], bf1, acc[0][1], 0, 0, 0); \
      acc[1][1] = __builtin_amdgcn_mfma_f32_32x32x16_bf16(vf[1][kfi], bf1, acc[1][1], 0, 0, 0); \
    }                                                                            \
  }

  for (int it = 0; it < 9; it++){
    FSTEP(kfA, kfB, 2*it,     0)
    FSTEP(kfB, kfA, 2*it + 1, 1)
  }
  #undef FSTEP

  // ---- cross-wave lsum reduction ----
  lsum0 += __shfl_xor(lsum0, 32);
  lsum1 += __shfl_xor(lsum1, 32);
  __syncthreads();               // all P traffic done; reuse-safe
  if (h == 0){
    lred[w][ln]      = lsum0;
    lred[w][32 + ln] = lsum1;
  }
  __syncthreads();

  // ---- epilogue: out = gamma*(O/lsum) + x ----
  float gmv = gamma_p[0];
  #pragma unroll
  for (int nn = 0; nn < 2; nn++){
    int n = n0 + nn*32 + ln;
    int nl = nn*32 + ln;
    float s = lred[0][nl] + lred[1][nl] + lred[2][nl] + lred[3][nl];
    float f = gmv / s;
    #pragma unroll
    for (int cf = 0; cf < 2; cf++){
      #pragma unroll
      for (int rr = 0; rr < 16; rr++){
        int c = ch*256 + w*64 + cf*32 + (rr & 3) + 8*(rr >> 2) + 4*h;
        size_t idx = ((size_t)b*C_ + c)*N_ + n;
        out[idx] = acc[cf][nn][rr]*f + x[idx];
      }
    }
  }
}

extern "C" void kernel_launch(void* const* d_in, const int* in_sizes, int n_in,
                              void* d_out, int out_size, void* d_ws, size_t ws_size,
                              hipStream_t stream) {
  (void)in_sizes; (void)n_in; (void)out_size; (void)ws_size;
  const float* x  = (const float*)d_in[0];
  const float* Wq = (const float*)d_in[1];
  const float* bq = (const float*)d_in[2];
  const float* Wk = (const float*)d_in[3];
  const float* bk = (const float*)d_in[4];
  const float* Wv = (const float*)d_in[5];
  const float* bv = (const float*)d_in[6];
  const float* gm = (const float*)d_in[7];
  float* out = (float*)d_out;

  unsigned short* xt = (unsigned short*)d_ws;                 // [B][N][C] bf16
  unsigned short* qw = xt + (size_t)B_*N_*C_;                 // [B][N][64] (centered, *log2e/512)
  unsigned short* kw = qw + (size_t)B_*N_*CQ;                 // [B][N][64]
  unsigned short* vw = kw + (size_t)B_*N_*CQ;                 // [B][C][N] (m-permuted)

  k_transpose<<<2304, 256, 0, stream>>>(x, xt);
  k_proj<0><<<288, 256, 0, stream>>>(xt, Wq, bq, qw);
  k_proj<1><<<288, 256, 0, stream>>>(xt, Wk, bk, kw);
  k_proj<2><<<2304, 256, 0, stream>>>(xt, Wv, bv, vw);
  k_attn<<<576, 256, 0, stream>>>(qw, kw, vw, x, gm, out);
}

// Round 8
// 155.724 us; speedup vs baseline: 1.5959x; 1.5959x over previous
//
#include <hip/hip_runtime.h>

#define B_ 8
#define C_ 512
#define N_ 2304
#define CQ 64

typedef float f32x4 __attribute__((ext_vector_type(4)));
typedef float f32x16 __attribute__((ext_vector_type(16)));
typedef short bf16x8 __attribute__((ext_vector_type(8)));
typedef unsigned short u16x8 __attribute__((ext_vector_type(8)));
typedef int i32x4 __attribute__((ext_vector_type(4)));

__device__ __forceinline__ unsigned short f2bf(float f){
  union { float f; unsigned int u; } v; v.f = f;
  unsigned int r = (v.u + 0x7fffu + ((v.u >> 16) & 1u)) >> 16;
  return (unsigned short)r;
}

__device__ __forceinline__ void gload_lds16(const void* g, void* l){
  __builtin_amdgcn_global_load_lds(
      (const __attribute__((address_space(1))) unsigned int*)g,
      (__attribute__((address_space(3))) unsigned int*)l, 16, 0, 0);
}

// ---------------- transpose: x [B][C][N] f32 -> xt [B][N][C] bf16 ----------------
__global__ __launch_bounds__(256) void k_transpose(const float* __restrict__ x,
                                                   unsigned short* __restrict__ xt){
  __shared__ float T[64*68];
  int i = blockIdx.x;
  int b = i & 7; int r = i >> 3;
  int ct = r & 7, nt = r >> 3;
  int c0 = ct << 6, n0 = nt << 6;
  int t = threadIdx.x;
  {
    int c = t >> 2, nn = (t & 3) << 4;
    const float* src = x + ((size_t)b*C_ + c0 + c)*N_ + n0 + nn;
    #pragma unroll
    for (int q = 0; q < 4; q++){
      f32x4 v = *(const f32x4*)(src + q*4);
      *(f32x4*)&T[c*68 + nn + q*4] = v;
    }
  }
  __syncthreads();
  {
    int n = t >> 2, cs = (t & 3) << 4;
    u16x8 h0, h1;
    #pragma unroll
    for (int ii = 0; ii < 8; ii++) h0[ii] = f2bf(T[(cs+ii)*68 + n]);
    #pragma unroll
    for (int ii = 0; ii < 8; ii++) h1[ii] = f2bf(T[(cs+8+ii)*68 + n]);
    unsigned short* d = xt + ((size_t)b*N_ + n0 + n)*C_ + c0 + cs;
    *(u16x8*)d = h0;
    *(u16x8*)(d + 8) = h1;
  }
}

// ---------------- projection GEMM ----------------
// MODE 0: Q -> center over o, scale log2e/512, store [B][N][64] bf16
// MODE 1: K -> store [B][N][64] bf16
// MODE 2: V -> store [B][C][N] bf16 with m-perm (bit2<->bit3 pairing)
template<int MODE>
__global__ __launch_bounds__(256) void k_proj(const unsigned short* __restrict__ xt,
                                              const float* __restrict__ Wm,
                                              const float* __restrict__ bias,
                                              unsigned short* __restrict__ outw){
  __shared__ short Al[64*40];
  __shared__ short Bl[64*40];
  __shared__ float T[64*68];
  int i = blockIdx.x;
  int b = i & 7; int r = i >> 3;
  int nt, o0;
  if (MODE == 2){ nt = r >> 3; o0 = (r & 7) << 6; } else { nt = r; o0 = 0; }
  int n0 = nt << 6;
  int t = threadIdx.x; int w = t >> 6; int l = t & 63;
  int cl = l & 15, g = l >> 4;
  int col = (w << 4) + cl;

  f32x4 acc[4];
  #pragma unroll
  for (int nf = 0; nf < 4; nf++) acc[nf] = (f32x4){0.f,0.f,0.f,0.f};

  for (int kk = 0; kk < 16; kk++){
    int c0k = kk << 5;
    {
      int n = t >> 2, cs8 = (t & 3) << 3;
      u16x8 v = *(const u16x8*)(xt + ((size_t)b*N_ + n0 + n)*C_ + c0k + cs8);
      *(u16x8*)&Al[n*40 + cs8] = v;
    }
    {
      int o = t >> 2, cs8 = (t & 3) << 3;
      const float* s = Wm + (size_t)(o0 + o)*C_ + c0k + cs8;
      f32x4 v0 = *(const f32x4*)s;
      f32x4 v1 = *(const f32x4*)(s + 4);
      u16x8 h;
      #pragma unroll
      for (int j = 0; j < 4; j++) h[j] = f2bf(v0[j]);
      #pragma unroll
      for (int j = 0; j < 4; j++) h[4+j] = f2bf(v1[j]);
      *(u16x8*)&Bl[o*40 + cs8] = h;
    }
    __syncthreads();
    bf16x8 bfr = *(const bf16x8*)&Bl[col*40 + (g << 3)];
    #pragma unroll
    for (int nf = 0; nf < 4; nf++){
      bf16x8 afr = *(const bf16x8*)&Al[((nf << 4) + cl)*40 + (g << 3)];
      acc[nf] = __builtin_amdgcn_mfma_f32_16x16x32_bf16(afr, bfr, acc[nf], 0, 0, 0);
    }
    __syncthreads();
  }

  float bvv = bias[o0 + col];
  #pragma unroll
  for (int nf = 0; nf < 4; nf++)
    #pragma unroll
    for (int rr = 0; rr < 4; rr++)
      T[((nf << 4) + (g << 2) + rr)*68 + col] = acc[nf][rr] + bvv;
  __syncthreads();

  if (MODE == 2){
    int o = t >> 2, j = t & 3;
    u16x8 h0, h1;
    #pragma unroll
    for (int ii = 0; ii < 8; ii++){
      int q2 = (ii & 3) | ((ii & 4) << 1);
      h0[ii] = f2bf(T[(j*16 + q2)*68 + o]);
    }
    #pragma unroll
    for (int ii = 0; ii < 8; ii++){
      int q2 = ((ii & 3) | ((ii & 4) << 1)) + 4;
      h1[ii] = f2bf(T[(j*16 + q2)*68 + o]);
    }
    unsigned short* d = outw + ((size_t)b*C_ + o0 + o)*N_ + n0 + (j << 4);
    *(u16x8*)d = h0;
    *(u16x8*)(d + 8) = h1;
  } else {
    int n = t >> 2, j = t & 3;
    float vals[16]; float s = 0.f;
    #pragma unroll
    for (int ii = 0; ii < 16; ii++){ vals[ii] = T[n*68 + (j << 4) + ii]; s += vals[ii]; }
    s += __shfl_xor(s, 1); s += __shfl_xor(s, 2);
    float mean = (MODE == 0) ? s * (1.f/64.f) : 0.f;
    float scl  = (MODE == 0) ? (1.44269504089f/512.f) : 1.f;
    u16x8 h0, h1;
    #pragma unroll
    for (int ii = 0; ii < 8; ii++) h0[ii] = f2bf((vals[ii]   - mean) * scl);
    #pragma unroll
    for (int ii = 0; ii < 8; ii++) h1[ii] = f2bf((vals[8+ii] - mean) * scl);
    unsigned short* d = outw + ((size_t)b*N_ + n0 + n)*CQ + (j << 4);
    *(u16x8*)d = h0;
    *(u16x8*)(d + 8) = h1;
  }
}

// ---------------- S + exp2 -> P (blocked frag-ready layout), K-prefetch pipelined ----------------
__global__ __launch_bounds__(256) void k_sexp(const unsigned short* __restrict__ qw,
                                              const unsigned short* __restrict__ kw,
                                              unsigned short* __restrict__ Pl,
                                              float* __restrict__ lsum_part,
                                              int b0, int bsh){
  int bid = blockIdx.x;
  int bl = bid & ((1 << bsh) - 1);
  int b = b0 + bl;
  int r = bid >> bsh;
  int ms = r & 3; int nt = r >> 2;
  int t = threadIdx.x; int w = t >> 6; int l = t & 63;
  int h = l >> 5, ln = l & 31;
  int nf = w & 1, mh = w >> 1;
  int n = nt*64 + nf*32 + ln;

  const unsigned short* qb = qw + ((size_t)b*N_ + n)*CQ + h*8;
  bf16x8 qf[4];
  #pragma unroll
  for (int kq = 0; kq < 4; kq++) qf[kq] = *(const bf16x8*)(qb + kq*16);

  int mb32base = ms*18 + mh*9;
  const unsigned short* ks0 = kw + ((size_t)b*N_ + ln)*CQ + h*8 + (size_t)mb32base*32*CQ;
  unsigned short* pb = Pl + ((size_t)bl*144*N_ + n)*16 + h*8;

  float lsum = 0.f;
  bf16x8 ka[4], kc[4];
  #pragma unroll
  for (int kq = 0; kq < 4; kq++) ka[kq] = *(const bf16x8*)(ks0 + kq*16);

  #define SEXP_BODY(MF, KF, KN, PFOFF)                                          \
  {                                                                             \
    _Pragma("unroll")                                                           \
    for (int kq = 0; kq < 4; kq++)                                              \
      KN[kq] = *(const bf16x8*)(ks0 + (size_t)(PFOFF)*32*CQ + kq*16);           \
    f32x16 sv;                                                                  \
    _Pragma("unroll")                                                           \
    for (int rr = 0; rr < 16; rr++) sv[rr] = 0.f;                               \
    _Pragma("unroll")                                                           \
    for (int kq = 0; kq < 4; kq++)                                              \
      sv = __builtin_amdgcn_mfma_f32_32x32x16_bf16(KF[kq], qf[kq], sv, 0, 0, 0);\
    float e[16];                                                                \
    _Pragma("unroll")                                                           \
    for (int rr = 0; rr < 16; rr++) e[rr] = exp2f(sv[rr]);                      \
    _Pragma("unroll")                                                           \
    for (int rr = 0; rr < 16; rr++) lsum += e[rr];                              \
    unsigned int pd[8];                                                         \
    _Pragma("unroll")                                                           \
    for (int j = 0; j < 8; j++)                                                 \
      asm("v_cvt_pk_bf16_f32 %0, %1, %2" : "=v"(pd[j]) : "v"(e[2*j]), "v"(e[2*j+1])); \
    i32x4 lo = (i32x4){(int)pd[0],(int)pd[1],(int)pd[2],(int)pd[3]};            \
    i32x4 hi = (i32x4){(int)pd[4],(int)pd[5],(int)pd[6],(int)pd[7]};            \
    unsigned short* d = pb + (size_t)((mb32base + (MF))*2)*N_*16;               \
    *(i32x4*)d = lo;                                                            \
    *(i32x4*)(d + (size_t)N_*16) = hi;                                          \
  }

  #pragma unroll
  for (int it = 0; it < 4; it++){
    SEXP_BODY(2*it,     ka, kc, 2*it + 1)
    SEXP_BODY(2*it + 1, kc, ka, 2*it + 2)
  }
  SEXP_BODY(8, ka, kc, 8)
  #undef SEXP_BODY

  lsum += __shfl_xor(lsum, 32);
  if (l < 32)
    lsum_part[((size_t)bl*8 + ms*2 + mh)*N_ + n] = lsum;
}

// ---------------- PV GEMM: 128c x 128n, BK=64, A 3-buf LDS + B 3-buf regs (2-deep) ----------------
// out[b][c][n] = gamma * (sum_m V[c][m] P[n][m]) / lsum[n] + x[b][c][n]
__global__ __launch_bounds__(256, 1) void k_pv(const unsigned short* __restrict__ vw,
                                               const unsigned short* __restrict__ Pl,
                                               const float* __restrict__ lsum_part,
                                               const float* __restrict__ x,
                                               const float* __restrict__ gamma_p,
                                               float* __restrict__ out,
                                               int b0, int bsh){
  __shared__ __attribute__((aligned(16))) short At[3][128*64];   // 3 x 16 KB

  int bid = blockIdx.x;
  int bl = bid & ((1 << bsh) - 1);
  int b = b0 + bl;
  int r = bid >> bsh;
  int cb = r & 3; int nb = r >> 2;          // cb 0..3, nb 0..17
  int c0 = cb*128, n0g = nb*128;
  int t = threadIdx.x; int w = t >> 6; int l = t & 63;
  int h = l >> 5, ln = l & 31;
  int wc = w & 1, wn = w >> 1;

  // --- A staging: thread covers granules G = w*256 + j*64 + l (j=0..3) ---
  int gc = ((l & 7) - (l >> 3)) & 7;
  const unsigned short* asrc0 = vw + ((size_t)b*C_ + c0 + w*32 + (l >> 3))*N_ + gc*8;
  // --- A frag read byte offsets ---
  int aro[2][4];
  #pragma unroll
  for (int cf = 0; cf < 2; cf++)
    #pragma unroll
    for (int mb = 0; mb < 4; mb++){
      int row = wc*64 + cf*32 + ln;
      aro[cf][mb] = (row*8 + ((mb*2 + h + row) & 7)) * 16;
    }
  // --- B: per-lane offsets into Pl slab ---
  const unsigned short* Pb = Pl + (size_t)bl*144*N_*16;
  size_t bstep = (size_t)N_*16;              // one 16-m block (shorts)
  int boff[2];
  #pragma unroll
  for (int nf = 0; nf < 2; nf++)
    boff[nf] = (n0g + wn*64 + nf*32 + ln)*16 + h*8;

  f32x16 acc[2][2];
  #pragma unroll
  for (int cf = 0; cf < 2; cf++)
    #pragma unroll
    for (int nf = 0; nf < 2; nf++)
      #pragma unroll
      for (int rr = 0; rr < 16; rr++) acc[cf][nf][rr] = 0.f;

  bf16x8 B0[2][4], B1[2][4], B2[2][4];

  // ---- prologue: stage A(0), A(1); load B(0), B(1) ----
  #pragma unroll
  for (int j = 0; j < 4; j++)
    gload_lds16(asrc0 + (size_t)j*8*N_, &At[0][w*2048 + j*512]);
  #pragma unroll
  for (int j = 0; j < 4; j++)
    gload_lds16(asrc0 + (size_t)j*8*N_ + 64, &At[1][w*2048 + j*512]);
  #pragma unroll
  for (int nf = 0; nf < 2; nf++)
    #pragma unroll
    for (int mb = 0; mb < 4; mb++)
      B0[nf][mb] = *(const bf16x8*)(Pb + (size_t)mb*bstep + boff[nf]);
  #pragma unroll
  for (int nf = 0; nf < 2; nf++)
    #pragma unroll
    for (int mb = 0; mb < 4; mb++)
      B1[nf][mb] = *(const bf16x8*)(Pb + (size_t)(4 + mb)*bstep + boff[nf]);
  asm volatile("s_waitcnt vmcnt(20)" ::: "memory");   // A(0) landed
  __builtin_amdgcn_s_barrier();
  __builtin_amdgcn_sched_barrier(0);

  // Step t: read A(t) frags, stage A(t+2), load B(t+2), MFMA with B(t) (loaded 2 ago).
  // In-flight at barrier: B(t+1)8 + A(t+2)4 + B(t+2)8 = 20  -> A(t+1) guaranteed landed.
  #define PV_STEP(KT, RD, WR, BC, BN)                                           \
  {                                                                             \
    const char* Ab = (const char*)At[RD];                                       \
    bf16x8 a_[2][4];                                                            \
    _Pragma("unroll")                                                           \
    for (int cf = 0; cf < 2; cf++)                                              \
      _Pragma("unroll")                                                         \
      for (int mb = 0; mb < 4; mb++)                                            \
        a_[cf][mb] = *(const bf16x8*)(Ab + aro[cf][mb]);                        \
    int m2 = ((KT) + 2 < 36) ? ((KT) + 2)*64 : 0;                               \
    _Pragma("unroll")                                                           \
    for (int j = 0; j < 4; j++)                                                 \
      gload_lds16(asrc0 + (size_t)j*8*N_ + m2, &At[WR][w*2048 + j*512]);        \
    {                                                                           \
      size_t mb2 = (size_t)((((KT) + 2 < 36) ? ((KT) + 2)*4 : 0));              \
      _Pragma("unroll")                                                         \
      for (int nf = 0; nf < 2; nf++)                                            \
        _Pragma("unroll")                                                       \
        for (int mb = 0; mb < 4; mb++)                                          \
          BN[nf][mb] = *(const bf16x8*)(Pb + (mb2 + mb)*bstep + boff[nf]);      \
    }                                                                           \
    _Pragma("unroll")                                                           \
    for (int cf = 0; cf < 2; cf++)                                              \
      _Pragma("unroll")                                                         \
      for (int nf = 0; nf < 2; nf++)                                            \
        _Pragma("unroll")                                                       \
        for (int mb = 0; mb < 4; mb++)                                          \
          acc[cf][nf] = __builtin_amdgcn_mfma_f32_32x32x16_bf16(                \
              a_[cf][mb], BC[nf][mb], acc[cf][nf], 0, 0, 0);                    \
    asm volatile("s_waitcnt vmcnt(20) lgkmcnt(0)" ::: "memory");                \
    __builtin_amdgcn_s_barrier();                                               \
    __builtin_amdgcn_sched_barrier(0);                                          \
  }

  for (int it = 0; it < 6; it++){
    int kt = it*6;
    PV_STEP(kt+0, 0, 2, B0, B2)
    PV_STEP(kt+1, 1, 0, B1, B0)
    PV_STEP(kt+2, 2, 1, B2, B1)
    PV_STEP(kt+3, 0, 2, B0, B2)
    PV_STEP(kt+4, 1, 0, B1, B0)
    PV_STEP(kt+5, 2, 1, B2, B1)
  }
  #undef PV_STEP

  // ---- epilogue: out = gamma*(O/lsum) + x ----
  float gmv = gamma_p[0];
  #pragma unroll
  for (int nf = 0; nf < 2; nf++){
    int n = n0g + wn*64 + nf*32 + ln;
    float s = 0.f;
    #pragma unroll
    for (int j = 0; j < 8; j++) s += lsum_part[((size_t)bl*8 + j)*N_ + n];
    float f = gmv / s;
    #pragma unroll
    for (int cf = 0; cf < 2; cf++){
      #pragma unroll
      for (int rr = 0; rr < 16; rr++){
        int c = c0 + wc*64 + cf*32 + (rr & 3) + 8*(rr >> 2) + 4*h;
        size_t idx = ((size_t)b*C_ + c)*N_ + n;
        out[idx] = acc[cf][nf][rr]*f + x[idx];
      }
    }
  }
}

extern "C" void kernel_launch(void* const* d_in, const int* in_sizes, int n_in,
                              void* d_out, int out_size, void* d_ws, size_t ws_size,
                              hipStream_t stream) {
  (void)in_sizes; (void)n_in; (void)out_size;
  const float* x  = (const float*)d_in[0];
  const float* Wq = (const float*)d_in[1];
  const float* bq = (const float*)d_in[2];
  const float* Wk = (const float*)d_in[3];
  const float* bk = (const float*)d_in[4];
  const float* Wv = (const float*)d_in[5];
  const float* bv = (const float*)d_in[6];
  const float* gm = (const float*)d_in[7];
  float* out = (float*)d_out;

  const size_t xt_b   = (size_t)B_*N_*C_*2;
  const size_t qw_b   = (size_t)B_*N_*CQ*2;
  const size_t vw_b   = (size_t)B_*C_*N_*2;

  int nbg = 8, bsh = 3;
  for (;;){
    size_t pl_b   = (size_t)nbg*144*N_*16*2;
    size_t reg0   = pl_b > xt_b ? pl_b : xt_b;
    size_t lsum_b = (size_t)nbg*8*N_*4;
    size_t need   = reg0 + 2*qw_b + vw_b + lsum_b;
    if (need <= ws_size || nbg == 1) break;
    nbg >>= 1; bsh--;
  }
  size_t pl_b = (size_t)nbg*144*N_*16*2;
  size_t reg0 = pl_b > xt_b ? pl_b : xt_b;

  char* wsc = (char*)d_ws;
  unsigned short* Pl = (unsigned short*)wsc;
  unsigned short* xt = (unsigned short*)wsc;
  unsigned short* qw = (unsigned short*)(wsc + reg0);
  unsigned short* kw = (unsigned short*)(wsc + reg0 + qw_b);
  unsigned short* vw = (unsigned short*)(wsc + reg0 + 2*qw_b);
  float* lsum_part   = (float*)(wsc + reg0 + 2*qw_b + vw_b);

  k_transpose<<<2304, 256, 0, stream>>>(x, xt);
  k_proj<0><<<288, 256, 0, stream>>>(xt, Wq, bq, qw);
  k_proj<1><<<288, 256, 0, stream>>>(xt, Wk, bk, kw);
  k_proj<2><<<2304, 256, 0, stream>>>(xt, Wv, bv, vw);

  for (int b0 = 0; b0 < B_; b0 += nbg){
    k_sexp<<<144*nbg, 256, 0, stream>>>(qw, kw, Pl, lsum_part, b0, bsh);
    k_pv<<<72*nbg, 256, 0, stream>>>(vw, Pl, lsum_part, x, gm, out, b0, bsh);
  }
}